// Round 6
// baseline (205.315 us; speedup 1.0000x reference)
//
#include <hip/hip_runtime.h>

typedef __attribute__((ext_vector_type(4))) short short4v;
typedef __attribute__((ext_vector_type(8))) short short8v;
typedef __attribute__((ext_vector_type(2))) unsigned int uint2v;
typedef __attribute__((ext_vector_type(4))) unsigned int uint4v;
typedef __attribute__((ext_vector_type(4))) float f32x4;
typedef __attribute__((ext_vector_type(16))) float f32x16;

#define LSTRIDE 68                 // bf16 elems per LDS row (136 B; stride/8 odd -> conflict-free b64)
#define MATB (64 * LSTRIDE * 2)    // 8704 B per 64x64 bf16 matrix

// ---- fallback (round-5) layout ----
#define REGA 0
#define REGB (4 * MATB)
#define LDS_BYTES (8 * MATB)       // 69632
#define CFRAG_BYTES (7 * 4 * 2 * 4 * 1024)  // 229376
#define INIT_OFF CFRAG_BYTES                // + 32768

// ---- Karatsuba layout ----
#define KLDS (6 * MATB)            // 52224: mats 0=Trh 1=Trl 2=Tih 3=Til 4=Tsh 5=Tsl
#define KSLOT_STRIDE 49152         // 6 mats * 8192
#define CS_OFF (7 * KSLOT_STRIDE)  // 344064: 2 mats (Cs1 h/l)
#define KINIT_OFF (CS_OFF + 2 * 8192)  // 360448: 2 slots f32 (C0r, C0i-C0r)
#define KWS_NEED (KINIT_OFF + 32768)   // 393216

__device__ __forceinline__ short bf16h(float v) {
    union { float f; unsigned u; } x; x.f = v;
    unsigned r = x.u + 0x7FFFu + ((x.u >> 16) & 1u);
    return (short)(r >> 16);
}
__device__ __forceinline__ float bf16tof(short s) {
    union { unsigned u; float f; } x; x.u = ((unsigned)(unsigned short)s) << 16;
    return x.f;
}
struct HL { unsigned h, l; };
__device__ __forceinline__ HL split2(float v0, float v1) {
    unsigned hp, lp;
    asm("v_cvt_pk_bf16_f32 %0, %1, %2" : "=v"(hp) : "v"(v0), "v"(v1));
    union { unsigned u; float f; } a, b;
    a.u = hp << 16;
    b.u = hp & 0xffff0000u;
    float l0 = v0 - a.f, l1 = v1 - b.f;
    asm("v_cvt_pk_bf16_f32 %0, %1, %2" : "=v"(lp) : "v"(l0), "v"(l1));
    HL r; r.h = hp; r.l = lp; return r;
}
__device__ __forceinline__ f32x16 MF(short8v a, short8v b, f32x16 c) {
    return __builtin_amdgcn_mfma_f32_32x32x16_bf16(a, b, c, 0, 0, 0);
}
__device__ __forceinline__ short8v negf(short8v a) {
    uint4v u = __builtin_bit_cast(uint4v, a);
    u ^= 0x80008000u;
    return __builtin_bit_cast(short8v, u);
}

// ================= Karatsuba path =================

// prep: 96 blocks x 64
__global__ void pms_prep_k(const float* __restrict__ coef, char* __restrict__ wsb) {
    const int blk = blockIdx.x;
    const int lane = threadIdx.x;
    const int lrow = lane & 31, lhi = lane >> 5;
    if (blk < 84) {
        const int s = blk / 12, rem = blk % 12;
        const int mat = rem >> 1, qr = rem & 1;
        const int which = mat >> 1, lo = mat & 1;   // which: 0=Cr 1=Ci 2=Cd
        const float* Pr = coef + (size_t)((s + 1) * 2 + 0) * 4096;
        const float* Pi = coef + (size_t)((s + 1) * 2 + 1) * 4096;
        for (int t = 0; t < 4; ++t) {
            short8v o;
            #pragma unroll
            for (int j = 0; j < 8; ++j) {
                int idx = (16 * t + 8 * lhi + j) * 64 + 32 * qr + lrow;
                float v = (which == 0) ? Pr[idx] : (which == 1) ? Pi[idx] : (Pi[idx] - Pr[idx]);
                short hh = bf16h(v);
                o[j] = lo ? bf16h(v - bf16tof(hh)) : hh;
            }
            *(short8v*)(wsb + (size_t)s * KSLOT_STRIDE + mat * 8192 + qr * 4096 + t * 1024 + lane * 16) = o;
        }
    } else if (blk < 88) {
        const int id = blk - 84;
        const int lo = id >> 1, qr = id & 1;        // Cs1 = C1r + C1i
        const float* Pr = coef + (size_t)(1 * 2 + 0) * 4096;
        const float* Pi = coef + (size_t)(1 * 2 + 1) * 4096;
        for (int t = 0; t < 4; ++t) {
            short8v o;
            #pragma unroll
            for (int j = 0; j < 8; ++j) {
                int idx = (16 * t + 8 * lhi + j) * 64 + 32 * qr + lrow;
                float v = Pr[idx] + Pi[idx];
                short hh = bf16h(v);
                o[j] = lo ? bf16h(v - bf16tof(hh)) : hh;
            }
            *(short8v*)(wsb + CS_OFF + lo * 8192 + qr * 4096 + t * 1024 + lane * 16) = o;
        }
    } else {
        const int id = blk - 88;                    // [slot][qr][qc]
        const int qc = id & 1, qr = (id >> 1) & 1, slot = id >> 2;
        float* dst = (float*)(wsb + KINIT_OFF + (size_t)(((slot * 2 + qr) * 2 + qc) * 64 + lane) * 64);
        #pragma unroll
        for (int v = 0; v < 16; ++v) {
            int r = 32 * qr + (v & 3) + 8 * (v >> 2) + 4 * lhi;
            int c = 32 * qc + lrow;
            float c0r = coef[c * 64 + r];
            float c0i = coef[4096 + c * 64 + r];
            dst[v] = (slot == 0) ? c0r : (c0i - c0r);
        }
    }
}

__global__ __launch_bounds__(256, 2) void pms_main_k(
    const float* __restrict__ x, const char* __restrict__ wsb,
    float* __restrict__ out)
{
    extern __shared__ char smem[];
    const int tid  = threadIdx.x;
    const int lane = tid & 63;
    const int w    = tid >> 6;
    const int qr = w >> 1, qc = w & 1;
    const int lrow = lane & 31, lhi = lane >> 5;
    const size_t b = blockIdx.x;
    const float* xb = x + b * 8192;

    // ---- stage X: mats 0..5 = Xr,Xi,Xs each h/l (T_1 = X, Ts_1 = Xs) ----
    #pragma unroll
    for (int s = 0; s < 4; ++s) {
        int f = s * 1024 + tid * 4;          // 0..4095
        int m = f >> 6, c = f & 63;
        f32x4 vr = *(const f32x4*)(xb + f);
        f32x4 vi = *(const f32x4*)(xb + 4096 + f);
        f32x4 vs;
        #pragma unroll
        for (int j = 0; j < 4; ++j) vs[j] = vr[j] + vi[j];
        HL r01 = split2(vr[0], vr[1]), r23 = split2(vr[2], vr[3]);
        HL i01 = split2(vi[0], vi[1]), i23 = split2(vi[2], vi[3]);
        HL s01 = split2(vs[0], vs[1]), s23 = split2(vs[2], vs[3]);
        int off = (m * LSTRIDE + c) * 2;
        uint2v u;
        u[0] = r01.h; u[1] = r23.h; *(uint2v*)(smem + 0 * MATB + off) = u;
        u[0] = r01.l; u[1] = r23.l; *(uint2v*)(smem + 1 * MATB + off) = u;
        u[0] = i01.h; u[1] = i23.h; *(uint2v*)(smem + 2 * MATB + off) = u;
        u[0] = i01.l; u[1] = i23.l; *(uint2v*)(smem + 3 * MATB + off) = u;
        u[0] = s01.h; u[1] = s23.h; *(uint2v*)(smem + 4 * MATB + off) = u;
        u[0] = s01.l; u[1] = s23.l; *(uint2v*)(smem + 5 * MATB + off) = u;
    }
    __syncthreads();

    // ---- persistent A-fragments of Xr^T, Xi^T, Xs^T (h/l) ----
    short8v xa[3][2][4];
    #pragma unroll
    for (int pi = 0; pi < 3; ++pi)
    #pragma unroll
    for (int hl = 0; hl < 2; ++hl)
    #pragma unroll
    for (int t = 0; t < 4; ++t) {
        const short* mp = (const short*)(smem + (pi * 2 + hl) * MATB);
        short8v a;
        #pragma unroll
        for (int j = 0; j < 8; ++j)
            a[j] = mp[(16 * t + 8 * lhi + j) * LSTRIDE + 32 * qr + lrow];
        xa[pi][hl][t] = a;
    }

    // ---- accumulators ----
    f32x16 accRr, accQ;
    {
        const f32x4* p0 = (const f32x4*)(wsb + KINIT_OFF + (size_t)(((0 + qr) * 2 + qc) * 64 + lane) * 64);
        #pragma unroll
        for (int g = 0; g < 4; ++g) {
            f32x4 a = p0[g];
            #pragma unroll
            for (int j = 0; j < 4; ++j) { accRr[4 * g + j] = a[j]; accQ[4 * g + j] = 0.f; }
        }
    }

    auto ldB = [&](int mat, int t) -> short8v {
        const short4v* p = (const short4v*)(smem + mat * MATB
                             + (32 * qc + lrow) * (LSTRIDE * 2) + 32 * t + 16 * lhi);
        short4v a = p[0], c4 = p[1];
        short8v r;
        #pragma unroll
        for (int j = 0; j < 4; ++j) { r[j] = a[j]; r[j + 4] = c4[j]; }
        return r;
    };

    f32x16 m1, m2, m3;

    // fold m1/m2/m3 -> T_k (6 mats, in place). Call with reads already barriered.
    auto foldWrite = [&]() {
        const int c = 32 * qc + lrow;
        f32x16 aTr, aTi, aTs;
        #pragma unroll
        for (int j = 0; j < 16; ++j) {
            float ar = m1[j] - m2[j];
            float ai = m3[j] - m1[j] - m2[j];
            aTr[j] = ar; aTi[j] = ai; aTs[j] = ar + ai;
        }
        #pragma unroll
        for (int g = 0; g < 4; ++g) {
            int rbse = 32 * qr + 8 * g + 4 * lhi;
            int off = (c * LSTRIDE + rbse) * 2;
            HL a01 = split2(aTr[4 * g + 0], aTr[4 * g + 1]);
            HL a23 = split2(aTr[4 * g + 2], aTr[4 * g + 3]);
            HL b01 = split2(aTi[4 * g + 0], aTi[4 * g + 1]);
            HL b23 = split2(aTi[4 * g + 2], aTi[4 * g + 3]);
            HL c01 = split2(aTs[4 * g + 0], aTs[4 * g + 1]);
            HL c23 = split2(aTs[4 * g + 2], aTs[4 * g + 3]);
            uint2v u;
            u[0] = a01.h; u[1] = a23.h; *(uint2v*)(smem + 0 * MATB + off) = u;
            u[0] = a01.l; u[1] = a23.l; *(uint2v*)(smem + 1 * MATB + off) = u;
            u[0] = b01.h; u[1] = b23.h; *(uint2v*)(smem + 2 * MATB + off) = u;
            u[0] = b01.l; u[1] = b23.l; *(uint2v*)(smem + 3 * MATB + off) = u;
            u[0] = c01.h; u[1] = c23.h; *(uint2v*)(smem + 4 * MATB + off) = u;
            u[0] = c01.l; u[1] = c23.l; *(uint2v*)(smem + 5 * MATB + off) = u;
        }
    };

    // ---- peeled k=2: apply C1 (quirk, kslot 0) + chain T2 = X*X ----
    {
        const char* cw = wsb;   // kslot 0
        #pragma unroll
        for (int j = 0; j < 16; ++j) { m1[j] = 0.f; m2[j] = 0.f; m3[j] = 0.f; }
        #pragma unroll
        for (int t = 0; t < 4; ++t) {
            short8v Crh = *(const short8v*)(cw + ((0 * 2 + qr) * 4 + t) * 1024 + lane * 16);
            short8v Crl = *(const short8v*)(cw + ((1 * 2 + qr) * 4 + t) * 1024 + lane * 16);
            short8v nCih = negf(*(const short8v*)(cw + ((2 * 2 + qr) * 4 + t) * 1024 + lane * 16));
            short8v nCil = negf(*(const short8v*)(cw + ((3 * 2 + qr) * 4 + t) * 1024 + lane * 16));
            short8v Cdh = *(const short8v*)(cw + ((4 * 2 + qr) * 4 + t) * 1024 + lane * 16);
            short8v Cdl = *(const short8v*)(cw + ((5 * 2 + qr) * 4 + t) * 1024 + lane * 16);
            short8v Csh = *(const short8v*)(wsb + CS_OFF + ((0 * 2 + qr) * 4 + t) * 1024 + lane * 16);
            short8v Csl = *(const short8v*)(wsb + CS_OFF + ((1 * 2 + qr) * 4 + t) * 1024 + lane * 16);
            short8v Brh = ldB(0, t), Brl = ldB(1, t);
            short8v Bih = ldB(2, t), Bil = ldB(3, t);
            short8v Bsh = ldB(4, t), Bsl = ldB(5, t);

            __builtin_amdgcn_s_setprio(1);
            accRr = MF(Crh, Brh, accRr);
            accQ  = MF(Cdh, Brh, accQ);
            m1    = MF(xa[0][0][t], Brh, m1);
            accRr = MF(nCih, Bih, accRr);
            accQ  = MF(Csh, Bih, accQ);
            m2    = MF(xa[1][0][t], Bih, m2);
            m3    = MF(xa[2][0][t], Bsh, m3);

            accRr = MF(Crh, Brl, accRr);
            accQ  = MF(Cdh, Brl, accQ);
            m1    = MF(xa[0][0][t], Brl, m1);
            accRr = MF(nCih, Bil, accRr);
            accQ  = MF(Csh, Bil, accQ);
            m2    = MF(xa[1][0][t], Bil, m2);
            m3    = MF(xa[2][0][t], Bsl, m3);

            accRr = MF(Crl, Brh, accRr);
            accQ  = MF(Cdl, Brh, accQ);
            m1    = MF(xa[0][1][t], Brh, m1);
            accRr = MF(nCil, Bih, accRr);
            accQ  = MF(Csl, Bih, accQ);
            m2    = MF(xa[1][1][t], Bih, m2);
            m3    = MF(xa[2][1][t], Bsh, m3);
            __builtin_amdgcn_s_setprio(0);
        }
        __syncthreads();
        foldWrite();
        __syncthreads();
    }

    // ---- k=3..7: apply C_{k-1} (kslot k-2, quirk-minus) + chain T_k ----
    for (int ks = 1; ks <= 5; ++ks) {
        const char* cw = wsb + (size_t)ks * KSLOT_STRIDE;
        #pragma unroll
        for (int j = 0; j < 16; ++j) { m1[j] = 0.f; m2[j] = 0.f; m3[j] = 0.f; }
        #pragma unroll
        for (int t = 0; t < 4; ++t) {
            short8v Crh = *(const short8v*)(cw + ((0 * 2 + qr) * 4 + t) * 1024 + lane * 16);
            short8v Crl = *(const short8v*)(cw + ((1 * 2 + qr) * 4 + t) * 1024 + lane * 16);
            short8v nCih = negf(*(const short8v*)(cw + ((2 * 2 + qr) * 4 + t) * 1024 + lane * 16));
            short8v nCil = negf(*(const short8v*)(cw + ((3 * 2 + qr) * 4 + t) * 1024 + lane * 16));
            short8v Cdh = *(const short8v*)(cw + ((4 * 2 + qr) * 4 + t) * 1024 + lane * 16);
            short8v Cdl = *(const short8v*)(cw + ((5 * 2 + qr) * 4 + t) * 1024 + lane * 16);
            short8v Brh = ldB(0, t), Brl = ldB(1, t);
            short8v Bih = ldB(2, t), Bil = ldB(3, t);
            short8v Bsh = ldB(4, t), Bsl = ldB(5, t);

            __builtin_amdgcn_s_setprio(1);
            accRr = MF(Crh, Brh, accRr);
            m1    = MF(xa[0][0][t], Brh, m1);
            accQ  = MF(Cdh, Bsh, accQ);
            accRr = MF(nCih, Bih, accRr);
            m2    = MF(xa[1][0][t], Bih, m2);
            m3    = MF(xa[2][0][t], Bsh, m3);

            accRr = MF(Crh, Brl, accRr);
            m1    = MF(xa[0][0][t], Brl, m1);
            accQ  = MF(Cdh, Bsl, accQ);
            accRr = MF(nCih, Bil, accRr);
            m2    = MF(xa[1][0][t], Bil, m2);
            m3    = MF(xa[2][0][t], Bsl, m3);

            accRr = MF(Crl, Brh, accRr);
            m1    = MF(xa[0][1][t], Brh, m1);
            accQ  = MF(Cdl, Bsh, accQ);
            accRr = MF(nCil, Bih, accRr);
            m2    = MF(xa[1][1][t], Bih, m2);
            m3    = MF(xa[2][1][t], Bsh, m3);
            __builtin_amdgcn_s_setprio(0);
        }
        __syncthreads();
        foldWrite();
        __syncthreads();
    }

    // ---- final: apply C7 (kslot 6) on T7 ----
    {
        const char* cw = wsb + (size_t)6 * KSLOT_STRIDE;
        #pragma unroll
        for (int t = 0; t < 4; ++t) {
            short8v Crh = *(const short8v*)(cw + ((0 * 2 + qr) * 4 + t) * 1024 + lane * 16);
            short8v Crl = *(const short8v*)(cw + ((1 * 2 + qr) * 4 + t) * 1024 + lane * 16);
            short8v nCih = negf(*(const short8v*)(cw + ((2 * 2 + qr) * 4 + t) * 1024 + lane * 16));
            short8v nCil = negf(*(const short8v*)(cw + ((3 * 2 + qr) * 4 + t) * 1024 + lane * 16));
            short8v Cdh = *(const short8v*)(cw + ((4 * 2 + qr) * 4 + t) * 1024 + lane * 16);
            short8v Cdl = *(const short8v*)(cw + ((5 * 2 + qr) * 4 + t) * 1024 + lane * 16);
            short8v Brh = ldB(0, t), Brl = ldB(1, t);
            short8v Bih = ldB(2, t), Bil = ldB(3, t);
            short8v Bsh = ldB(4, t), Bsl = ldB(5, t);

            __builtin_amdgcn_s_setprio(1);
            accRr = MF(Crh, Brh, accRr);
            accQ  = MF(Cdh, Bsh, accQ);
            accRr = MF(nCih, Bih, accRr);
            accRr = MF(Crh, Brl, accRr);
            accQ  = MF(Cdh, Bsl, accQ);
            accRr = MF(nCih, Bil, accRr);
            accRr = MF(Crl, Brh, accRr);
            accQ  = MF(Cdl, Bsh, accQ);
            accRr = MF(nCil, Bih, accRr);
            __builtin_amdgcn_s_setprio(0);
        }
    }

    // ---- epilogue: res_r = accRr; res_i = accRr + accQ + (C0i - C0r) ----
    f32x16 accRi;
    {
        const f32x4* p1 = (const f32x4*)(wsb + KINIT_OFF + (size_t)(((2 + qr) * 2 + qc) * 64 + lane) * 64);
        #pragma unroll
        for (int g = 0; g < 4; ++g) {
            f32x4 d = p1[g];
            #pragma unroll
            for (int j = 0; j < 4; ++j)
                accRi[4 * g + j] = accRr[4 * g + j] + accQ[4 * g + j] + d[j];
        }
    }
    __syncthreads();   // done reading T region
    {
        const int c = 32 * qc + lrow;
        #pragma unroll
        for (int g = 0; g < 4; ++g) {
            int rbse = 32 * qr + 8 * g + 4 * lhi;
            f32x4 vr, vi;
            #pragma unroll
            for (int j = 0; j < 4; ++j) { vr[j] = accRr[4 * g + j]; vi[j] = accRi[4 * g + j]; }
            *(f32x4*)(smem + (size_t)(0 * 4352 + c * LSTRIDE + rbse) * 4) = vr;
            *(f32x4*)(smem + (size_t)(1 * 4352 + c * LSTRIDE + rbse) * 4) = vi;
        }
    }
    __syncthreads();
    float* ob = out + b * 8192;
    #pragma unroll
    for (int s = 0; s < 8; ++s) {
        int f = s * 1024 + tid * 4;
        int p = f >> 12, m = (f >> 6) & 63, n = f & 63;
        *(f32x4*)(ob + f) = *(const f32x4*)(smem + (size_t)(p * 4352 + m * LSTRIDE + n) * 4);
    }
}

// ================= fallback (round-5, proven) =================

__global__ void pms_prep(const float* __restrict__ coef, char* __restrict__ wsb) {
    const int blk = blockIdx.x;
    const int lane = threadIdx.x;
    const int lrow = lane & 31, lhi = lane >> 5;
    if (blk < 56) {
        const int qr  = blk & 1;
        const int km  = blk >> 1;
        const int mat = km & 3;
        const int kk  = km >> 2;
        const int part = mat >> 1;
        const int lo   = mat & 1;
        const float* C = coef + (size_t)((kk + 1) * 2 + part) * 4096;
        for (int t = 0; t < 4; ++t) {
            short8v o;
            #pragma unroll
            for (int j = 0; j < 8; ++j) {
                int krow = 16 * t + 8 * lhi + j;
                int col  = 32 * qr + lrow;
                float v = C[krow * 64 + col];
                short hh = bf16h(v);
                o[j] = lo ? bf16h(v - bf16tof(hh)) : hh;
            }
            *(short8v*)(wsb + ((size_t)blk * 4 + t) * 1024 + lane * 16) = o;
        }
    } else {
        const int id = blk - 56;
        const int qc = id & 1, qr = (id >> 1) & 1, part = id >> 2;
        const float* C0 = coef + (size_t)part * 4096;
        float* dst = (float*)(wsb + INIT_OFF + (size_t)(((part * 2 + qr) * 2 + qc) * 64 + lane) * 64);
        #pragma unroll
        for (int v = 0; v < 16; ++v) {
            int r = 32 * qr + (v & 3) + 8 * (v >> 2) + 4 * lhi;
            int c = 32 * qc + lrow;
            dst[v] = C0[c * 64 + r];
        }
    }
}

__global__ __launch_bounds__(256, 2) void pms_main(
    const float* __restrict__ x, const char* __restrict__ wsb,
    float* __restrict__ out)
{
    extern __shared__ char smem[];
    const int tid  = threadIdx.x;
    const int lane = tid & 63;
    const int w    = tid >> 6;
    const int qr = w >> 1, qc = w & 1;
    const int lrow = lane & 31, lhi = lane >> 5;
    const size_t b = blockIdx.x;
    const float* xb = x + b * 8192;

    #pragma unroll
    for (int s = 0; s < 8; ++s) {
        int f = s * 1024 + tid * 4;
        int p = f >> 12, m = (f >> 6) & 63, c = f & 63;
        f32x4 v = *(const f32x4*)(xb + f);
        HL a01 = split2(v[0], v[1]);
        HL a23 = split2(v[2], v[3]);
        uint2v h, l;
        h[0] = a01.h; l[0] = a01.l;
        h[1] = a23.h; l[1] = a23.l;
        int off = (m * LSTRIDE + c) * 2;
        *(uint2v*)(smem + REGA + (p * 2 + 0) * MATB + off) = h;
        *(uint2v*)(smem + REGA + (p * 2 + 1) * MATB + off) = l;
    }
    __syncthreads();

    short8v xa[2][2][4];
    #pragma unroll
    for (int pi = 0; pi < 2; ++pi)
    #pragma unroll
    for (int hl = 0; hl < 2; ++hl)
    #pragma unroll
    for (int t = 0; t < 4; ++t) {
        const short* mp = (const short*)(smem + REGA + (pi * 2 + hl) * MATB);
        short8v a;
        #pragma unroll
        for (int j = 0; j < 8; ++j)
            a[j] = mp[(16 * t + 8 * lhi + j) * LSTRIDE + 32 * qr + lrow];
        xa[pi][hl][t] = a;
    }

    f32x16 accRr, accRi;
    {
        const f32x4* p0 = (const f32x4*)(wsb + INIT_OFF + (size_t)(((0 + qr) * 2 + qc) * 64 + lane) * 64);
        const f32x4* p1 = (const f32x4*)(wsb + INIT_OFF + (size_t)(((2 + qr) * 2 + qc) * 64 + lane) * 64);
        #pragma unroll
        for (int g = 0; g < 4; ++g) {
            f32x4 a = p0[g], c4 = p1[g];
            #pragma unroll
            for (int j = 0; j < 4; ++j) { accRr[4 * g + j] = a[j]; accRi[4 * g + j] = c4[j]; }
        }
    }

    auto ldB = [&](int rbase, int mat, int t) -> short8v {
        const short4v* p = (const short4v*)(smem + rbase + mat * MATB
                             + (32 * qc + lrow) * (LSTRIDE * 2) + 32 * t + 16 * lhi);
        short4v a = p[0], c4 = p[1];
        short8v r;
        #pragma unroll
        for (int j = 0; j < 4; ++j) { r[j] = a[j]; r[j + 4] = c4[j]; }
        return r;
    };

    int cur = REGA, nxt = REGB;

    for (int k = 2; k <= 7; ++k) {
        const char* cw = wsb + (size_t)(k - 2) * 32768;
        const bool k1 = (k == 2);

        short8v cRh[4], cRl[4], cIh[4], cIl[4];
        #pragma unroll
        for (int t = 0; t < 4; ++t) {
            cRh[t] = *(const short8v*)(cw + ((0 * 2 + qr) * 4 + t) * 1024 + lane * 16);
            cRl[t] = *(const short8v*)(cw + ((1 * 2 + qr) * 4 + t) * 1024 + lane * 16);
            cIh[t] = *(const short8v*)(cw + ((2 * 2 + qr) * 4 + t) * 1024 + lane * 16);
            cIl[t] = *(const short8v*)(cw + ((3 * 2 + qr) * 4 + t) * 1024 + lane * 16);
        }
        short8v Brh = ldB(cur, 0, 0), Brl = ldB(cur, 1, 0);
        short8v Bih = ldB(cur, 2, 0), Bil = ldB(cur, 3, 0);

        f32x16 aTr, aTi;
        #pragma unroll
        for (int v = 0; v < 16; ++v) { aTr[v] = 0.f; aTi[v] = 0.f; }

        #pragma unroll
        for (int t = 0; t < 4; ++t) {
            short8v Nrh, Nrl, Nih, Nil;
            if (t < 3) {
                Nrh = ldB(cur, 0, t + 1); Nrl = ldB(cur, 1, t + 1);
                Nih = ldB(cur, 2, t + 1); Nil = ldB(cur, 3, t + 1);
            }
            short8v nBih = negf(Bih), nBil = negf(Bil);
            short8v sBih = k1 ? Bih : nBih;
            short8v sBil = k1 ? Bil : nBil;

            __builtin_amdgcn_s_setprio(1);
            accRr = MF(cRh[t], Brh, accRr);
            accRi = MF(cIh[t], Brh, accRi);
            aTr   = MF(xa[0][0][t], Brh, aTr);
            aTi   = MF(xa[1][0][t], Brh, aTi);

            accRr = MF(cRh[t], Brl, accRr);
            accRi = MF(cIh[t], Brl, accRi);
            aTr   = MF(xa[0][0][t], Brl, aTr);
            aTi   = MF(xa[1][0][t], Brl, aTi);

            accRr = MF(cRl[t], Brh, accRr);
            accRi = MF(cIl[t], Brh, accRi);
            aTr   = MF(xa[0][1][t], Brh, aTr);
            aTi   = MF(xa[1][1][t], Brh, aTi);

            accRr = MF(cIh[t], nBih, accRr);
            accRi = MF(cRh[t], sBih, accRi);
            aTr   = MF(xa[1][0][t], nBih, aTr);
            aTi   = MF(xa[0][0][t], Bih, aTi);

            accRr = MF(cIh[t], nBil, accRr);
            accRi = MF(cRh[t], sBil, accRi);
            aTr   = MF(xa[1][0][t], nBil, aTr);
            aTi   = MF(xa[0][0][t], Bil, aTi);

            accRr = MF(cIl[t], nBih, accRr);
            accRi = MF(cRl[t], sBih, accRi);
            aTr   = MF(xa[1][1][t], nBih, aTr);
            aTi   = MF(xa[0][1][t], Bih, aTi);
            __builtin_amdgcn_s_setprio(0);

            if (t < 3) { Brh = Nrh; Brl = Nrl; Bih = Nih; Bil = Nil; }
        }

        {
            const int c = 32 * qc + lrow;
            #pragma unroll
            for (int g = 0; g < 4; ++g) {
                int rbse = 32 * qr + 8 * g + 4 * lhi;
                HL r01 = split2(aTr[4 * g + 0], aTr[4 * g + 1]);
                HL r23 = split2(aTr[4 * g + 2], aTr[4 * g + 3]);
                HL i01 = split2(aTi[4 * g + 0], aTi[4 * g + 1]);
                HL i23 = split2(aTi[4 * g + 2], aTi[4 * g + 3]);
                uint2v hr, lr, hi2, li2;
                hr[0] = r01.h; lr[0] = r01.l; hr[1] = r23.h; lr[1] = r23.l;
                hi2[0] = i01.h; li2[0] = i01.l; hi2[1] = i23.h; li2[1] = i23.l;
                int off = (c * LSTRIDE + rbse) * 2;
                *(uint2v*)(smem + nxt + 0 * MATB + off) = hr;
                *(uint2v*)(smem + nxt + 1 * MATB + off) = lr;
                *(uint2v*)(smem + nxt + 2 * MATB + off) = hi2;
                *(uint2v*)(smem + nxt + 3 * MATB + off) = li2;
            }
        }
        __syncthreads();
        int tmp = cur; cur = nxt; nxt = tmp;
    }

    {
        const char* cw = wsb + (size_t)6 * 32768;
        short8v cRh[4], cRl[4], cIh[4], cIl[4];
        #pragma unroll
        for (int t = 0; t < 4; ++t) {
            cRh[t] = *(const short8v*)(cw + ((0 * 2 + qr) * 4 + t) * 1024 + lane * 16);
            cRl[t] = *(const short8v*)(cw + ((1 * 2 + qr) * 4 + t) * 1024 + lane * 16);
            cIh[t] = *(const short8v*)(cw + ((2 * 2 + qr) * 4 + t) * 1024 + lane * 16);
            cIl[t] = *(const short8v*)(cw + ((3 * 2 + qr) * 4 + t) * 1024 + lane * 16);
        }
        short8v Brh = ldB(cur, 0, 0), Brl = ldB(cur, 1, 0);
        short8v Bih = ldB(cur, 2, 0), Bil = ldB(cur, 3, 0);
        #pragma unroll
        for (int t = 0; t < 4; ++t) {
            short8v Nrh, Nrl, Nih, Nil;
            if (t < 3) {
                Nrh = ldB(cur, 0, t + 1); Nrl = ldB(cur, 1, t + 1);
                Nih = ldB(cur, 2, t + 1); Nil = ldB(cur, 3, t + 1);
            }
            short8v nBih = negf(Bih), nBil = negf(Bil);

            __builtin_amdgcn_s_setprio(1);
            accRr = MF(cRh[t], Brh, accRr);
            accRi = MF(cIh[t], Brh, accRi);
            accRr = MF(cRh[t], Brl, accRr);
            accRi = MF(cIh[t], Brl, accRi);
            accRr = MF(cRl[t], Brh, accRr);
            accRi = MF(cIl[t], Brh, accRi);
            accRr = MF(cIh[t], nBih, accRr);
            accRi = MF(cRh[t], nBih, accRi);
            accRr = MF(cIh[t], nBil, accRr);
            accRi = MF(cRh[t], nBil, accRi);
            accRr = MF(cIl[t], nBih, accRr);
            accRi = MF(cRl[t], nBih, accRi);
            __builtin_amdgcn_s_setprio(0);

            if (t < 3) { Brh = Nrh; Brl = Nrl; Bih = Nih; Bil = Nil; }
        }
    }

    __syncthreads();
    {
        const int c = 32 * qc + lrow;
        #pragma unroll
        for (int g = 0; g < 4; ++g) {
            int rbse = 32 * qr + 8 * g + 4 * lhi;
            f32x4 vr, vi;
            #pragma unroll
            for (int j = 0; j < 4; ++j) { vr[j] = accRr[4 * g + j]; vi[j] = accRi[4 * g + j]; }
            *(f32x4*)(smem + nxt + (size_t)(0 * 4352 + c * LSTRIDE + rbse) * 4) = vr;
            *(f32x4*)(smem + nxt + (size_t)(1 * 4352 + c * LSTRIDE + rbse) * 4) = vi;
        }
    }
    __syncthreads();
    float* ob = out + b * 8192;
    #pragma unroll
    for (int s = 0; s < 8; ++s) {
        int f = s * 1024 + tid * 4;
        int p = f >> 12, m = (f >> 6) & 63, n = f & 63;
        *(f32x4*)(ob + f) = *(const f32x4*)(smem + nxt + (size_t)(p * 4352 + m * LSTRIDE + n) * 4);
    }
}

extern "C" void kernel_launch(void* const* d_in, const int* in_sizes, int n_in,
                              void* d_out, int out_size, void* d_ws, size_t ws_size,
                              hipStream_t stream) {
    const float* x    = (const float*)d_in[0];
    const float* coef = (const float*)d_in[1];
    float* out = (float*)d_out;
    char*  wsb = (char*)d_ws;
    const int B = in_sizes[0] / 8192;   // 2048

    if (ws_size >= (size_t)KWS_NEED) {
        pms_prep_k<<<96, 64, 0, stream>>>(coef, wsb);
        pms_main_k<<<B, 256, KLDS, stream>>>(x, wsb, out);
    } else {
        (void)hipFuncSetAttribute(reinterpret_cast<const void*>(&pms_main),
                                  hipFuncAttributeMaxDynamicSharedMemorySize, LDS_BYTES);
        pms_prep<<<64, 64, 0, stream>>>(coef, wsb);
        pms_main<<<B, 256, LDS_BYTES, stream>>>(x, wsb, out);
    }
}

// Round 7
// 189.116 us; speedup vs baseline: 1.0857x; 1.0857x over previous
//
#include <hip/hip_runtime.h>

typedef __attribute__((ext_vector_type(4))) short short4v;
typedef __attribute__((ext_vector_type(8))) short short8v;
typedef __attribute__((ext_vector_type(2))) unsigned int uint2v;
typedef __attribute__((ext_vector_type(4))) unsigned int uint4v;
typedef __attribute__((ext_vector_type(4))) float f32x4;
typedef __attribute__((ext_vector_type(16))) float f32x16;

#define LSTRIDE 68                 // bf16 elems per LDS row (136 B; stride/8 odd -> conflict-free b64)
#define MATB (64 * LSTRIDE * 2)    // 8704 B per 64x64 bf16 matrix

// LDS: 6 T mats (0=Trh 1=Trl 2=Tih 3=Til 4=Tsh 5=Tsl) + XSA frag-linear region
#define XSA (6 * MATB)             // 52224
#define KLDS (XSA + 16384)         // 68608 (<160K; 2 WG/CU)

// ws layout (pms_prep_k): [kslot 0..6][mat 0..5][qr][t][lane*16B]
// mat: 0=Cr_h 1=Cr_l 2=Ci_h 3=Ci_l 4=Cd_h 5=Cd_l   (Cd = Ci - Cr)
#define KSLOT_STRIDE 49152         // 6 mats * 8192
#define CS_OFF (7 * KSLOT_STRIDE)  // 344064: 2 mats (Cs1 h/l), Cs1 = C1r + C1i
#define KINIT_OFF (CS_OFF + 2 * 8192)  // 360448: 2 slots f32 (C0r, C0i-C0r)
#define KWS_NEED (KINIT_OFF + 32768)   // 393216 (proven available in round 6)

__device__ __forceinline__ short bf16h(float v) {
    union { float f; unsigned u; } x; x.f = v;
    unsigned r = x.u + 0x7FFFu + ((x.u >> 16) & 1u);
    return (short)(r >> 16);
}
__device__ __forceinline__ float bf16tof(short s) {
    union { unsigned u; float f; } x; x.u = ((unsigned)(unsigned short)s) << 16;
    return x.f;
}
struct HL { unsigned h, l; };
__device__ __forceinline__ HL split2(float v0, float v1) {
    unsigned hp, lp;
    asm("v_cvt_pk_bf16_f32 %0, %1, %2" : "=v"(hp) : "v"(v0), "v"(v1));
    union { unsigned u; float f; } a, b;
    a.u = hp << 16;
    b.u = hp & 0xffff0000u;
    float l0 = v0 - a.f, l1 = v1 - b.f;
    asm("v_cvt_pk_bf16_f32 %0, %1, %2" : "=v"(lp) : "v"(l0), "v"(l1));
    HL r; r.h = hp; r.l = lp; return r;
}
__device__ __forceinline__ f32x16 MF(short8v a, short8v b, f32x16 c) {
    return __builtin_amdgcn_mfma_f32_32x32x16_bf16(a, b, c, 0, 0, 0);
}
__device__ __forceinline__ short8v negf(short8v a) {
    uint4v u = __builtin_bit_cast(uint4v, a);
    u ^= 0x80008000u;
    return __builtin_bit_cast(short8v, u);
}

// 6 coefficient fragments of one kslot/t (Ci pre-negated at load)
struct CF { short8v crh, crl, ncih, ncil, cdh, cdl; };
__device__ __forceinline__ CF loadCF(const char* cw, int qr, int lane, int t) {
    CF c;
    c.crh  =      *(const short8v*)(cw + ((size_t)(0 * 2 + qr) * 4 + t) * 1024 + lane * 16);
    c.crl  =      *(const short8v*)(cw + ((size_t)(1 * 2 + qr) * 4 + t) * 1024 + lane * 16);
    c.ncih = negf(*(const short8v*)(cw + ((size_t)(2 * 2 + qr) * 4 + t) * 1024 + lane * 16));
    c.ncil = negf(*(const short8v*)(cw + ((size_t)(3 * 2 + qr) * 4 + t) * 1024 + lane * 16));
    c.cdh  =      *(const short8v*)(cw + ((size_t)(4 * 2 + qr) * 4 + t) * 1024 + lane * 16);
    c.cdl  =      *(const short8v*)(cw + ((size_t)(5 * 2 + qr) * 4 + t) * 1024 + lane * 16);
    return c;
}

// ---------------- prep (unchanged, proven round 6) ----------------
__global__ void pms_prep_k(const float* __restrict__ coef, char* __restrict__ wsb) {
    const int blk = blockIdx.x;
    const int lane = threadIdx.x;
    const int lrow = lane & 31, lhi = lane >> 5;
    if (blk < 84) {
        const int s = blk / 12, rem = blk % 12;
        const int mat = rem >> 1, qr = rem & 1;
        const int which = mat >> 1, lo = mat & 1;   // which: 0=Cr 1=Ci 2=Cd
        const float* Pr = coef + (size_t)((s + 1) * 2 + 0) * 4096;
        const float* Pi = coef + (size_t)((s + 1) * 2 + 1) * 4096;
        for (int t = 0; t < 4; ++t) {
            short8v o;
            #pragma unroll
            for (int j = 0; j < 8; ++j) {
                int idx = (16 * t + 8 * lhi + j) * 64 + 32 * qr + lrow;
                float v = (which == 0) ? Pr[idx] : (which == 1) ? Pi[idx] : (Pi[idx] - Pr[idx]);
                short hh = bf16h(v);
                o[j] = lo ? bf16h(v - bf16tof(hh)) : hh;
            }
            *(short8v*)(wsb + (size_t)s * KSLOT_STRIDE + mat * 8192 + qr * 4096 + t * 1024 + lane * 16) = o;
        }
    } else if (blk < 88) {
        const int id = blk - 84;
        const int lo = id >> 1, qr = id & 1;        // Cs1 = C1r + C1i
        const float* Pr = coef + (size_t)(1 * 2 + 0) * 4096;
        const float* Pi = coef + (size_t)(1 * 2 + 1) * 4096;
        for (int t = 0; t < 4; ++t) {
            short8v o;
            #pragma unroll
            for (int j = 0; j < 8; ++j) {
                int idx = (16 * t + 8 * lhi + j) * 64 + 32 * qr + lrow;
                float v = Pr[idx] + Pi[idx];
                short hh = bf16h(v);
                o[j] = lo ? bf16h(v - bf16tof(hh)) : hh;
            }
            *(short8v*)(wsb + CS_OFF + lo * 8192 + qr * 4096 + t * 1024 + lane * 16) = o;
        }
    } else {
        const int id = blk - 88;                    // [slot][qr][qc]
        const int qc = id & 1, qr = (id >> 1) & 1, slot = id >> 2;
        float* dst = (float*)(wsb + KINIT_OFF + (size_t)(((slot * 2 + qr) * 2 + qc) * 64 + lane) * 64);
        #pragma unroll
        for (int v = 0; v < 16; ++v) {
            int r = 32 * qr + (v & 3) + 8 * (v >> 2) + 4 * lhi;
            int c = 32 * qc + lrow;
            float c0r = coef[c * 64 + r];
            float c0i = coef[4096 + c * 64 + r];
            dst[v] = (slot == 0) ? c0r : (c0i - c0r);
        }
    }
}

// ---------------- main ----------------
__global__ __launch_bounds__(256, 2) void pms_main_k(
    const float* __restrict__ x, const char* __restrict__ wsb,
    float* __restrict__ out)
{
    extern __shared__ char smem[];
    const int tid  = threadIdx.x;
    const int lane = tid & 63;
    const int w    = tid >> 6;
    const int qr = w >> 1, qc = w & 1;
    const int lrow = lane & 31, lhi = lane >> 5;
    const size_t b = blockIdx.x;
    const float* xb = x + b * 8192;

    // ---- stage X: mats 0..5 = Xr,Xi,Xs each h/l (T_1 = X, Ts_1 = Xs) ----
    #pragma unroll
    for (int s = 0; s < 4; ++s) {
        int f = s * 1024 + tid * 4;          // 0..4095
        int m = f >> 6, c = f & 63;
        f32x4 vr = *(const f32x4*)(xb + f);
        f32x4 vi = *(const f32x4*)(xb + 4096 + f);
        f32x4 vs;
        #pragma unroll
        for (int j = 0; j < 4; ++j) vs[j] = vr[j] + vi[j];
        HL r01 = split2(vr[0], vr[1]), r23 = split2(vr[2], vr[3]);
        HL i01 = split2(vi[0], vi[1]), i23 = split2(vi[2], vi[3]);
        HL s01 = split2(vs[0], vs[1]), s23 = split2(vs[2], vs[3]);
        int off = (m * LSTRIDE + c) * 2;
        uint2v u;
        u[0] = r01.h; u[1] = r23.h; *(uint2v*)(smem + 0 * MATB + off) = u;
        u[0] = r01.l; u[1] = r23.l; *(uint2v*)(smem + 1 * MATB + off) = u;
        u[0] = i01.h; u[1] = i23.h; *(uint2v*)(smem + 2 * MATB + off) = u;
        u[0] = i01.l; u[1] = i23.l; *(uint2v*)(smem + 3 * MATB + off) = u;
        u[0] = s01.h; u[1] = s23.h; *(uint2v*)(smem + 4 * MATB + off) = u;
        u[0] = s01.l; u[1] = s23.l; *(uint2v*)(smem + 5 * MATB + off) = u;
    }
    __syncthreads();

    // ---- persistent A-fragments of Xr^T, Xi^T only (64 VGPRs) ----
    short8v xa[2][2][4];
    #pragma unroll
    for (int pi = 0; pi < 2; ++pi)
    #pragma unroll
    for (int hl = 0; hl < 2; ++hl)
    #pragma unroll
    for (int t = 0; t < 4; ++t) {
        const short* mp = (const short*)(smem + (pi * 2 + hl) * MATB);
        short8v a;
        #pragma unroll
        for (int j = 0; j < 8; ++j)
            a[j] = mp[(16 * t + 8 * lhi + j) * LSTRIDE + 32 * qr + lrow];
        xa[pi][hl][t] = a;
    }

    // ---- Xs^T A-frags -> XSA (frag-linear LDS); wave (qr,qc) covers t=2qc..2qc+1 ----
    #pragma unroll
    for (int hl = 0; hl < 2; ++hl)
    #pragma unroll
    for (int tt = 0; tt < 2; ++tt) {
        int t = 2 * qc + tt;
        const short* mp = (const short*)(smem + (4 + hl) * MATB);
        short8v a;
        #pragma unroll
        for (int j = 0; j < 8; ++j)
            a[j] = mp[(16 * t + 8 * lhi + j) * LSTRIDE + 32 * qr + lrow];
        *(short8v*)(smem + XSA + ((size_t)(hl * 2 + qr) * 4 + t) * 1024 + lane * 16) = a;
    }
    __syncthreads();

    // ---- accumulators ----
    f32x16 accRr, accQ;
    {
        const f32x4* p0 = (const f32x4*)(wsb + KINIT_OFF + (size_t)(((0 + qr) * 2 + qc) * 64 + lane) * 64);
        #pragma unroll
        for (int g = 0; g < 4; ++g) {
            f32x4 a = p0[g];
            #pragma unroll
            for (int j = 0; j < 4; ++j) { accRr[4 * g + j] = a[j]; accQ[4 * g + j] = 0.f; }
        }
    }

    auto ldB = [&](int mat, int t) -> short8v {
        const short4v* p = (const short4v*)(smem + mat * MATB
                             + (32 * qc + lrow) * (LSTRIDE * 2) + 32 * t + 16 * lhi);
        short4v a = p[0], c4 = p[1];
        short8v r;
        #pragma unroll
        for (int j = 0; j < 4; ++j) { r[j] = a[j]; r[j + 4] = c4[j]; }
        return r;
    };
    auto ldXS = [&](int hl, int t) -> short8v {
        return *(const short8v*)(smem + XSA + ((size_t)(hl * 2 + qr) * 4 + t) * 1024 + lane * 16);
    };

    f32x16 m1, m2, m3;

    // fold m1/m2/m3 -> T_k (6 mats, in place). Call between barriers.
    auto foldWrite = [&]() {
        const int c = 32 * qc + lrow;
        f32x16 aTr, aTi, aTs;
        #pragma unroll
        for (int j = 0; j < 16; ++j) {
            float ar = m1[j] - m2[j];
            float ai = m3[j] - m1[j] - m2[j];
            aTr[j] = ar; aTi[j] = ai; aTs[j] = ar + ai;
        }
        #pragma unroll
        for (int g = 0; g < 4; ++g) {
            int rbse = 32 * qr + 8 * g + 4 * lhi;
            int off = (c * LSTRIDE + rbse) * 2;
            HL a01 = split2(aTr[4 * g + 0], aTr[4 * g + 1]);
            HL a23 = split2(aTr[4 * g + 2], aTr[4 * g + 3]);
            HL b01 = split2(aTi[4 * g + 0], aTi[4 * g + 1]);
            HL b23 = split2(aTi[4 * g + 2], aTi[4 * g + 3]);
            HL c01 = split2(aTs[4 * g + 0], aTs[4 * g + 1]);
            HL c23 = split2(aTs[4 * g + 2], aTs[4 * g + 3]);
            uint2v u;
            u[0] = a01.h; u[1] = a23.h; *(uint2v*)(smem + 0 * MATB + off) = u;
            u[0] = a01.l; u[1] = a23.l; *(uint2v*)(smem + 1 * MATB + off) = u;
            u[0] = b01.h; u[1] = b23.h; *(uint2v*)(smem + 2 * MATB + off) = u;
            u[0] = b01.l; u[1] = b23.l; *(uint2v*)(smem + 3 * MATB + off) = u;
            u[0] = c01.h; u[1] = c23.h; *(uint2v*)(smem + 4 * MATB + off) = u;
            u[0] = c01.l; u[1] = c23.l; *(uint2v*)(smem + 5 * MATB + off) = u;
        }
    };

    // also re-write Ts_k rebuild after XSA (frags stay valid: XSA holds Xs only, never T)
    // NOTE: m3 in iteration k uses Xs^T (chain operand), B from Ts_{k-1} (mats 4/5). XSA is Xs only. OK.

    CF cnxt;   // next-iteration t=0 prefetch

    // ---- peeled k=2: apply C1 (quirk, kslot 0) + chain T2 = X*X ----
    {
        const char* cw = wsb;   // kslot 0
        CF c0 = loadCF(cw, qr, lane, 0);
        short8v csh0 = *(const short8v*)(wsb + CS_OFF + ((size_t)(0 * 2 + qr) * 4 + 0) * 1024 + lane * 16);
        short8v csl0 = *(const short8v*)(wsb + CS_OFF + ((size_t)(1 * 2 + qr) * 4 + 0) * 1024 + lane * 16);
        #pragma unroll
        for (int j = 0; j < 16; ++j) { m1[j] = 0.f; m2[j] = 0.f; m3[j] = 0.f; }
        #pragma unroll
        for (int t = 0; t < 4; ++t) {
            CF c1; short8v csh1, csl1;
            if (t < 3) {
                c1 = loadCF(cw, qr, lane, t + 1);
                csh1 = *(const short8v*)(wsb + CS_OFF + ((size_t)(0 * 2 + qr) * 4 + t + 1) * 1024 + lane * 16);
                csl1 = *(const short8v*)(wsb + CS_OFF + ((size_t)(1 * 2 + qr) * 4 + t + 1) * 1024 + lane * 16);
            }
            short8v Brh = ldB(0, t), Brl = ldB(1, t);
            short8v Bih = ldB(2, t), Bil = ldB(3, t);
            short8v Bsh = ldB(4, t), Bsl = ldB(5, t);
            short8v xsh = ldXS(0, t), xsl = ldXS(1, t);

            __builtin_amdgcn_s_setprio(1);
            accRr = MF(c0.crh, Brh, accRr);
            accQ  = MF(c0.cdh, Brh, accQ);
            m1    = MF(xa[0][0][t], Brh, m1);
            accRr = MF(c0.ncih, Bih, accRr);
            accQ  = MF(csh0, Bih, accQ);
            m2    = MF(xa[1][0][t], Bih, m2);
            m3    = MF(xsh, Bsh, m3);

            accRr = MF(c0.crh, Brl, accRr);
            accQ  = MF(c0.cdh, Brl, accQ);
            m1    = MF(xa[0][0][t], Brl, m1);
            accRr = MF(c0.ncih, Bil, accRr);
            accQ  = MF(csh0, Bil, accQ);
            m2    = MF(xa[1][0][t], Bil, m2);
            m3    = MF(xsh, Bsl, m3);

            accRr = MF(c0.crl, Brh, accRr);
            accQ  = MF(c0.cdl, Brh, accQ);
            m1    = MF(xa[0][1][t], Brh, m1);
            accRr = MF(c0.ncil, Bih, accRr);
            accQ  = MF(csl0, Bih, accQ);
            m2    = MF(xa[1][1][t], Bih, m2);
            m3    = MF(xsl, Bsh, m3);
            __builtin_amdgcn_s_setprio(0);

            if (t < 3) { c0 = c1; csh0 = csh1; csl0 = csl1; }
        }
        cnxt = loadCF(wsb + (size_t)1 * KSLOT_STRIDE, qr, lane, 0);  // hide under fold
        __syncthreads();
        foldWrite();
        __syncthreads();
    }

    // ---- k=3..7: apply C_{k-1} (kslot ks) + chain T_k ----
    for (int ks = 1; ks <= 5; ++ks) {
        const char* cw = wsb + (size_t)ks * KSLOT_STRIDE;
        CF c0 = cnxt;
        #pragma unroll
        for (int j = 0; j < 16; ++j) { m1[j] = 0.f; m2[j] = 0.f; m3[j] = 0.f; }
        #pragma unroll
        for (int t = 0; t < 4; ++t) {
            CF c1;
            if (t < 3) c1 = loadCF(cw, qr, lane, t + 1);
            short8v Brh = ldB(0, t), Brl = ldB(1, t);
            short8v Bih = ldB(2, t), Bil = ldB(3, t);
            short8v Bsh = ldB(4, t), Bsl = ldB(5, t);
            short8v xsh = ldXS(0, t), xsl = ldXS(1, t);

            __builtin_amdgcn_s_setprio(1);
            accRr = MF(c0.crh, Brh, accRr);
            m1    = MF(xa[0][0][t], Brh, m1);
            accQ  = MF(c0.cdh, Bsh, accQ);
            accRr = MF(c0.ncih, Bih, accRr);
            m2    = MF(xa[1][0][t], Bih, m2);
            m3    = MF(xsh, Bsh, m3);

            accRr = MF(c0.crh, Brl, accRr);
            m1    = MF(xa[0][0][t], Brl, m1);
            accQ  = MF(c0.cdh, Bsl, accQ);
            accRr = MF(c0.ncih, Bil, accRr);
            m2    = MF(xa[1][0][t], Bil, m2);
            m3    = MF(xsh, Bsl, m3);

            accRr = MF(c0.crl, Brh, accRr);
            m1    = MF(xa[0][1][t], Brh, m1);
            accQ  = MF(c0.cdl, Bsh, accQ);
            accRr = MF(c0.ncil, Bih, accRr);
            m2    = MF(xa[1][1][t], Bih, m2);
            m3    = MF(xsl, Bsh, m3);
            __builtin_amdgcn_s_setprio(0);

            if (t < 3) c0 = c1;
        }
        cnxt = loadCF(wsb + (size_t)(ks + 1) * KSLOT_STRIDE, qr, lane, 0);  // ks=5 -> kslot 6 (final)
        __syncthreads();
        foldWrite();
        __syncthreads();
    }

    // ---- final: apply C7 (kslot 6) on T7 ----
    {
        const char* cw = wsb + (size_t)6 * KSLOT_STRIDE;
        CF c0 = cnxt;
        #pragma unroll
        for (int t = 0; t < 4; ++t) {
            CF c1;
            if (t < 3) c1 = loadCF(cw, qr, lane, t + 1);
            short8v Brh = ldB(0, t), Brl = ldB(1, t);
            short8v Bih = ldB(2, t), Bil = ldB(3, t);
            short8v Bsh = ldB(4, t), Bsl = ldB(5, t);

            __builtin_amdgcn_s_setprio(1);
            accRr = MF(c0.crh, Brh, accRr);
            accQ  = MF(c0.cdh, Bsh, accQ);
            accRr = MF(c0.ncih, Bih, accRr);
            accRr = MF(c0.crh, Brl, accRr);
            accQ  = MF(c0.cdh, Bsl, accQ);
            accRr = MF(c0.ncih, Bil, accRr);
            accRr = MF(c0.crl, Brh, accRr);
            accQ  = MF(c0.cdl, Bsh, accQ);
            accRr = MF(c0.ncil, Bih, accRr);
            __builtin_amdgcn_s_setprio(0);

            if (t < 3) c0 = c1;
        }
    }

    // ---- epilogue: res_r = accRr; res_i = accRr + accQ + (C0i - C0r) ----
    f32x16 accRi;
    {
        const f32x4* p1 = (const f32x4*)(wsb + KINIT_OFF + (size_t)(((2 + qr) * 2 + qc) * 64 + lane) * 64);
        #pragma unroll
        for (int g = 0; g < 4; ++g) {
            f32x4 d = p1[g];
            #pragma unroll
            for (int j = 0; j < 4; ++j)
                accRi[4 * g + j] = accRr[4 * g + j] + accQ[4 * g + j] + d[j];
        }
    }
    __syncthreads();   // done reading T region
    {
        const int c = 32 * qc + lrow;
        #pragma unroll
        for (int g = 0; g < 4; ++g) {
            int rbse = 32 * qr + 8 * g + 4 * lhi;
            f32x4 vr, vi;
            #pragma unroll
            for (int j = 0; j < 4; ++j) { vr[j] = accRr[4 * g + j]; vi[j] = accRi[4 * g + j]; }
            *(f32x4*)(smem + (size_t)(0 * 4352 + c * LSTRIDE + rbse) * 4) = vr;
            *(f32x4*)(smem + (size_t)(1 * 4352 + c * LSTRIDE + rbse) * 4) = vi;
        }
    }
    __syncthreads();
    float* ob = out + b * 8192;
    #pragma unroll
    for (int s = 0; s < 8; ++s) {
        int f = s * 1024 + tid * 4;
        int p = f >> 12, m = (f >> 6) & 63, n = f & 63;
        *(f32x4*)(ob + f) = *(const f32x4*)(smem + (size_t)(p * 4352 + m * LSTRIDE + n) * 4);
    }
}

extern "C" void kernel_launch(void* const* d_in, const int* in_sizes, int n_in,
                              void* d_out, int out_size, void* d_ws, size_t ws_size,
                              hipStream_t stream) {
    const float* x    = (const float*)d_in[0];
    const float* coef = (const float*)d_in[1];
    float* out = (float*)d_out;
    char*  wsb = (char*)d_ws;
    const int B = in_sizes[0] / 8192;   // 2048

    (void)hipFuncSetAttribute(reinterpret_cast<const void*>(&pms_main_k),
                              hipFuncAttributeMaxDynamicSharedMemorySize, KLDS);

    pms_prep_k<<<96, 64, 0, stream>>>(coef, wsb);
    pms_main_k<<<B, 256, KLDS, stream>>>(x, wsb, out);
}

// Round 8
// 178.173 us; speedup vs baseline: 1.1523x; 1.0614x over previous
//
#include <hip/hip_runtime.h>

typedef __attribute__((ext_vector_type(4))) short short4v;
typedef __attribute__((ext_vector_type(8))) short short8v;
typedef __attribute__((ext_vector_type(2))) unsigned int uint2v;
typedef __attribute__((ext_vector_type(4))) unsigned int uint4v;
typedef __attribute__((ext_vector_type(4))) float f32x4;
typedef __attribute__((ext_vector_type(16))) float f32x16;

#define LSTRIDE 68                 // bf16 elems per LDS row (136 B; stride/8 odd -> conflict-free b64)
#define MATB (64 * LSTRIDE * 2)    // 8704 B per 64x64 bf16 matrix
#define KLDS (6 * MATB)            // 52224: mats 0=Trh 1=Trl 2=Tih 3=Til 4=Tsh 5=Tsl (in-place)

// ws layout (pms_prep_k, proven round 6/7): [kslot 0..6][mat 0..5][qr][t][lane*16B]
// mat: 0=Cr_h 1=Cr_l 2=Ci_h 3=Ci_l 4=Cd_h 5=Cd_l   (Cd = Ci - Cr)
#define KSLOT_STRIDE 49152         // 6 mats * 8192
#define CS_OFF (7 * KSLOT_STRIDE)  // 344064: 2 mats (Cs1 h/l), Cs1 = C1r + C1i
#define KINIT_OFF (CS_OFF + 2 * 8192)  // 360448: 2 slots f32 (C0r, C0i-C0r)

__device__ __forceinline__ short bf16h(float v) {
    union { float f; unsigned u; } x; x.f = v;
    unsigned r = x.u + 0x7FFFu + ((x.u >> 16) & 1u);
    return (short)(r >> 16);
}
__device__ __forceinline__ float bf16tof(short s) {
    union { unsigned u; float f; } x; x.u = ((unsigned)(unsigned short)s) << 16;
    return x.f;
}
struct HL { unsigned h, l; };
__device__ __forceinline__ HL split2(float v0, float v1) {
    unsigned hp, lp;
    asm("v_cvt_pk_bf16_f32 %0, %1, %2" : "=v"(hp) : "v"(v0), "v"(v1));
    union { unsigned u; float f; } a, b;
    a.u = hp << 16;
    b.u = hp & 0xffff0000u;
    float l0 = v0 - a.f, l1 = v1 - b.f;
    asm("v_cvt_pk_bf16_f32 %0, %1, %2" : "=v"(lp) : "v"(l0), "v"(l1));
    HL r; r.h = hp; r.l = lp; return r;
}
__device__ __forceinline__ f32x16 MF(short8v a, short8v b, f32x16 c) {
    return __builtin_amdgcn_mfma_f32_32x32x16_bf16(a, b, c, 0, 0, 0);
}
__device__ __forceinline__ short8v negf(short8v a) {
    uint4v u = __builtin_bit_cast(uint4v, a);
    u ^= 0x80008000u;
    return __builtin_bit_cast(short8v, u);
}

// 6 coefficient fragments of one kslot/t (Ci pre-negated at load)
struct CF { short8v crh, crl, ncih, ncil, cdh, cdl; };
__device__ __forceinline__ CF loadCF(const char* cw, int qr, int lane, int t) {
    CF c;
    c.crh  =      *(const short8v*)(cw + ((size_t)(0 * 2 + qr) * 4 + t) * 1024 + lane * 16);
    c.crl  =      *(const short8v*)(cw + ((size_t)(1 * 2 + qr) * 4 + t) * 1024 + lane * 16);
    c.ncih = negf(*(const short8v*)(cw + ((size_t)(2 * 2 + qr) * 4 + t) * 1024 + lane * 16));
    c.ncil = negf(*(const short8v*)(cw + ((size_t)(3 * 2 + qr) * 4 + t) * 1024 + lane * 16));
    c.cdh  =      *(const short8v*)(cw + ((size_t)(4 * 2 + qr) * 4 + t) * 1024 + lane * 16);
    c.cdl  =      *(const short8v*)(cw + ((size_t)(5 * 2 + qr) * 4 + t) * 1024 + lane * 16);
    return c;
}

// ---------------- prep (unchanged, proven round 6/7) ----------------
__global__ void pms_prep_k(const float* __restrict__ coef, char* __restrict__ wsb) {
    const int blk = blockIdx.x;
    const int lane = threadIdx.x;
    const int lrow = lane & 31, lhi = lane >> 5;
    if (blk < 84) {
        const int s = blk / 12, rem = blk % 12;
        const int mat = rem >> 1, qr = rem & 1;
        const int which = mat >> 1, lo = mat & 1;   // which: 0=Cr 1=Ci 2=Cd
        const float* Pr = coef + (size_t)((s + 1) * 2 + 0) * 4096;
        const float* Pi = coef + (size_t)((s + 1) * 2 + 1) * 4096;
        for (int t = 0; t < 4; ++t) {
            short8v o;
            #pragma unroll
            for (int j = 0; j < 8; ++j) {
                int idx = (16 * t + 8 * lhi + j) * 64 + 32 * qr + lrow;
                float v = (which == 0) ? Pr[idx] : (which == 1) ? Pi[idx] : (Pi[idx] - Pr[idx]);
                short hh = bf16h(v);
                o[j] = lo ? bf16h(v - bf16tof(hh)) : hh;
            }
            *(short8v*)(wsb + (size_t)s * KSLOT_STRIDE + mat * 8192 + qr * 4096 + t * 1024 + lane * 16) = o;
        }
    } else if (blk < 88) {
        const int id = blk - 84;
        const int lo = id >> 1, qr = id & 1;        // Cs1 = C1r + C1i
        const float* Pr = coef + (size_t)(1 * 2 + 0) * 4096;
        const float* Pi = coef + (size_t)(1 * 2 + 1) * 4096;
        for (int t = 0; t < 4; ++t) {
            short8v o;
            #pragma unroll
            for (int j = 0; j < 8; ++j) {
                int idx = (16 * t + 8 * lhi + j) * 64 + 32 * qr + lrow;
                float v = Pr[idx] + Pi[idx];
                short hh = bf16h(v);
                o[j] = lo ? bf16h(v - bf16tof(hh)) : hh;
            }
            *(short8v*)(wsb + CS_OFF + lo * 8192 + qr * 4096 + t * 1024 + lane * 16) = o;
        }
    } else {
        const int id = blk - 88;                    // [slot][qr][qc]
        const int qc = id & 1, qr = (id >> 1) & 1, slot = id >> 2;
        float* dst = (float*)(wsb + KINIT_OFF + (size_t)(((slot * 2 + qr) * 2 + qc) * 64 + lane) * 64);
        #pragma unroll
        for (int v = 0; v < 16; ++v) {
            int r = 32 * qr + (v & 3) + 8 * (v >> 2) + 4 * lhi;
            int c = 32 * qc + lrow;
            float c0r = coef[c * 64 + r];
            float c0i = coef[4096 + c * 64 + r];
            dst[v] = (slot == 0) ? c0r : (c0i - c0r);
        }
    }
}

// ---------------- main ----------------
__global__ __launch_bounds__(256, 2) void pms_main_k(
    const float* __restrict__ x, const char* __restrict__ wsb,
    float* __restrict__ out)
{
    extern __shared__ char smem[];
    const int tid  = threadIdx.x;
    const int lane = tid & 63;
    const int w    = tid >> 6;
    const int qr = w >> 1, qc = w & 1;
    const int lrow = lane & 31, lhi = lane >> 5;
    const size_t b = blockIdx.x;
    const float* xb = x + b * 8192;

    // ---- stage X into mats 0..3 (Xr h/l, Xi h/l). Ts_1 never read; mats 4/5 filled at first fold ----
    #pragma unroll
    for (int s = 0; s < 4; ++s) {
        int f = s * 1024 + tid * 4;          // 0..4095
        int m = f >> 6, c = f & 63;
        f32x4 vr = *(const f32x4*)(xb + f);
        f32x4 vi = *(const f32x4*)(xb + 4096 + f);
        HL r01 = split2(vr[0], vr[1]), r23 = split2(vr[2], vr[3]);
        HL i01 = split2(vi[0], vi[1]), i23 = split2(vi[2], vi[3]);
        int off = (m * LSTRIDE + c) * 2;
        uint2v u;
        u[0] = r01.h; u[1] = r23.h; *(uint2v*)(smem + 0 * MATB + off) = u;
        u[0] = r01.l; u[1] = r23.l; *(uint2v*)(smem + 1 * MATB + off) = u;
        u[0] = i01.h; u[1] = i23.h; *(uint2v*)(smem + 2 * MATB + off) = u;
        u[0] = i01.l; u[1] = i23.l; *(uint2v*)(smem + 3 * MATB + off) = u;
    }
    __syncthreads();

    // ---- persistent A-fragments of Xr^T, Xi^T (64 regs, same envelope as round 5) ----
    short8v xa[2][2][4];
    #pragma unroll
    for (int pi = 0; pi < 2; ++pi)
    #pragma unroll
    for (int hl = 0; hl < 2; ++hl)
    #pragma unroll
    for (int t = 0; t < 4; ++t) {
        const short* mp = (const short*)(smem + (pi * 2 + hl) * MATB);
        short8v a;
        #pragma unroll
        for (int j = 0; j < 8; ++j)
            a[j] = mp[(16 * t + 8 * lhi + j) * LSTRIDE + 32 * qr + lrow];
        xa[pi][hl][t] = a;
    }

    // ---- accumulators: accRr init C0r; accQ init 0 ----
    f32x16 accRr, accQ;
    {
        const f32x4* p0 = (const f32x4*)(wsb + KINIT_OFF + (size_t)(((0 + qr) * 2 + qc) * 64 + lane) * 64);
        #pragma unroll
        for (int g = 0; g < 4; ++g) {
            f32x4 a = p0[g];
            #pragma unroll
            for (int j = 0; j < 4; ++j) { accRr[4 * g + j] = a[j]; accQ[4 * g + j] = 0.f; }
        }
    }

    auto ldB = [&](int mat, int t) -> short8v {
        const short4v* p = (const short4v*)(smem + mat * MATB
                             + (32 * qc + lrow) * (LSTRIDE * 2) + 32 * t + 16 * lhi);
        short4v a = p[0], c4 = p[1];
        short8v r;
        #pragma unroll
        for (int j = 0; j < 4; ++j) { r[j] = a[j]; r[j + 4] = c4[j]; }
        return r;
    };

    // fold aTr/aTi -> T_k (6 mats incl Ts = aTr+aTi, in place, between barriers)
    auto foldWrite = [&](const f32x16& aTr, const f32x16& aTi) {
        const int c = 32 * qc + lrow;
        #pragma unroll
        for (int g = 0; g < 4; ++g) {
            int rbse = 32 * qr + 8 * g + 4 * lhi;
            int off = (c * LSTRIDE + rbse) * 2;
            float s0 = aTr[4 * g + 0] + aTi[4 * g + 0];
            float s1 = aTr[4 * g + 1] + aTi[4 * g + 1];
            float s2 = aTr[4 * g + 2] + aTi[4 * g + 2];
            float s3 = aTr[4 * g + 3] + aTi[4 * g + 3];
            HL a01 = split2(aTr[4 * g + 0], aTr[4 * g + 1]);
            HL a23 = split2(aTr[4 * g + 2], aTr[4 * g + 3]);
            HL b01 = split2(aTi[4 * g + 0], aTi[4 * g + 1]);
            HL b23 = split2(aTi[4 * g + 2], aTi[4 * g + 3]);
            HL c01 = split2(s0, s1);
            HL c23 = split2(s2, s3);
            uint2v u;
            u[0] = a01.h; u[1] = a23.h; *(uint2v*)(smem + 0 * MATB + off) = u;
            u[0] = a01.l; u[1] = a23.l; *(uint2v*)(smem + 1 * MATB + off) = u;
            u[0] = b01.h; u[1] = b23.h; *(uint2v*)(smem + 2 * MATB + off) = u;
            u[0] = b01.l; u[1] = b23.l; *(uint2v*)(smem + 3 * MATB + off) = u;
            u[0] = c01.h; u[1] = c23.h; *(uint2v*)(smem + 4 * MATB + off) = u;
            u[0] = c01.l; u[1] = c23.l; *(uint2v*)(smem + 5 * MATB + off) = u;
        }
    };

    CF cnxt;   // next-kslot t=0 prefetch

    // ---- peeled k=2: apply C1 (quirk: accQ += Cd*Tr + Cs*Ti) + chain T2 = X*X ----
    {
        const char* cw = wsb;   // kslot 0
        f32x16 aTr, aTi;
        #pragma unroll
        for (int j = 0; j < 16; ++j) { aTr[j] = 0.f; aTi[j] = 0.f; }
        CF c0 = loadCF(cw, qr, lane, 0);
        short8v Brh = ldB(0, 0), Brl = ldB(1, 0);
        short8v Bih = ldB(2, 0), Bil = ldB(3, 0);
        #pragma unroll
        for (int t = 0; t < 4; ++t) {
            CF c1; short8v Nrh, Nrl, Nih, Nil;
            if (t < 3) {
                c1 = loadCF(cw, qr, lane, t + 1);
                Nrh = ldB(0, t + 1); Nrl = ldB(1, t + 1);
                Nih = ldB(2, t + 1); Nil = ldB(3, t + 1);
            }
            short8v csh = *(const short8v*)(wsb + CS_OFF + ((size_t)(0 * 2 + qr) * 4 + t) * 1024 + lane * 16);
            short8v csl = *(const short8v*)(wsb + CS_OFF + ((size_t)(1 * 2 + qr) * 4 + t) * 1024 + lane * 16);
            short8v nBih = negf(Bih), nBil = negf(Bil);

            __builtin_amdgcn_s_setprio(1);
            accRr = MF(c0.crh, Brh, accRr);
            aTr   = MF(xa[0][0][t], Brh, aTr);
            aTi   = MF(xa[1][0][t], Brh, aTi);
            accQ  = MF(c0.cdh, Brh, accQ);

            accRr = MF(c0.crh, Brl, accRr);
            aTr   = MF(xa[0][0][t], Brl, aTr);
            aTi   = MF(xa[1][0][t], Brl, aTi);
            accQ  = MF(c0.cdh, Brl, accQ);

            accRr = MF(c0.crl, Brh, accRr);
            aTr   = MF(xa[0][1][t], Brh, aTr);
            aTi   = MF(xa[1][1][t], Brh, aTi);
            accQ  = MF(c0.cdl, Brh, accQ);

            accRr = MF(c0.ncih, Bih, accRr);
            aTr   = MF(xa[1][0][t], nBih, aTr);
            aTi   = MF(xa[0][0][t], Bih, aTi);
            accQ  = MF(csh, Bih, accQ);

            accRr = MF(c0.ncih, Bil, accRr);
            aTr   = MF(xa[1][0][t], nBil, aTr);
            aTi   = MF(xa[0][0][t], Bil, aTi);
            accQ  = MF(csh, Bil, accQ);

            accRr = MF(c0.ncil, Bih, accRr);
            aTr   = MF(xa[1][1][t], nBih, aTr);
            aTi   = MF(xa[0][1][t], Bih, aTi);
            accQ  = MF(csl, Bih, accQ);
            __builtin_amdgcn_s_setprio(0);

            if (t < 3) { c0 = c1; Brh = Nrh; Brl = Nrl; Bih = Nih; Bil = Nil; }
        }
        cnxt = loadCF(wsb + (size_t)1 * KSLOT_STRIDE, qr, lane, 0);
        __syncthreads();
        foldWrite(aTr, aTi);
        __syncthreads();
    }

    // ---- k=3..7 (ks=1..5): coeff 9/t (accQ += Cd*Ts) + chain 12/t ----
    for (int ks = 1; ks <= 5; ++ks) {
        const char* cw = wsb + (size_t)ks * KSLOT_STRIDE;
        f32x16 aTr, aTi;
        #pragma unroll
        for (int j = 0; j < 16; ++j) { aTr[j] = 0.f; aTi[j] = 0.f; }
        CF c0 = cnxt;
        short8v Brh = ldB(0, 0), Brl = ldB(1, 0);
        short8v Bih = ldB(2, 0), Bil = ldB(3, 0);
        #pragma unroll
        for (int t = 0; t < 4; ++t) {
            CF c1; short8v Nrh, Nrl, Nih, Nil;
            if (t < 3) {
                c1 = loadCF(cw, qr, lane, t + 1);
                Nrh = ldB(0, t + 1); Nrl = ldB(1, t + 1);
                Nih = ldB(2, t + 1); Nil = ldB(3, t + 1);
            }
            short8v Bsh = ldB(4, t), Bsl = ldB(5, t);   // JIT; consumed late
            short8v nBih = negf(Bih), nBil = negf(Bil);

            __builtin_amdgcn_s_setprio(1);
            accRr = MF(c0.crh, Brh, accRr);
            aTr   = MF(xa[0][0][t], Brh, aTr);
            aTi   = MF(xa[1][0][t], Brh, aTi);

            accRr = MF(c0.crh, Brl, accRr);
            aTr   = MF(xa[0][0][t], Brl, aTr);
            aTi   = MF(xa[1][0][t], Brl, aTi);

            accRr = MF(c0.crl, Brh, accRr);
            aTr   = MF(xa[0][1][t], Brh, aTr);
            aTi   = MF(xa[1][1][t], Brh, aTi);

            accRr = MF(c0.ncih, Bih, accRr);
            aTr   = MF(xa[1][0][t], nBih, aTr);
            aTi   = MF(xa[0][0][t], Bih, aTi);
            accQ  = MF(c0.cdh, Bsh, accQ);

            accRr = MF(c0.ncih, Bil, accRr);
            aTr   = MF(xa[1][0][t], nBil, aTr);
            aTi   = MF(xa[0][0][t], Bil, aTi);
            accQ  = MF(c0.cdh, Bsl, accQ);

            accRr = MF(c0.ncil, Bih, accRr);
            aTr   = MF(xa[1][1][t], nBih, aTr);
            aTi   = MF(xa[0][1][t], Bih, aTi);
            accQ  = MF(c0.cdl, Bsh, accQ);
            __builtin_amdgcn_s_setprio(0);

            if (t < 3) { c0 = c1; Brh = Nrh; Brl = Nrl; Bih = Nih; Bil = Nil; }
        }
        cnxt = loadCF(wsb + (size_t)(ks + 1) * KSLOT_STRIDE, qr, lane, 0);  // ks=5 -> kslot 6
        __syncthreads();
        foldWrite(aTr, aTi);
        __syncthreads();
    }

    // ---- final: apply C7 (kslot 6) on T7: 9 MFMAs/t ----
    {
        CF c0 = cnxt;
        const char* cw = wsb + (size_t)6 * KSLOT_STRIDE;
        short8v Brh = ldB(0, 0), Brl = ldB(1, 0);
        short8v Bih = ldB(2, 0), Bil = ldB(3, 0);
        #pragma unroll
        for (int t = 0; t < 4; ++t) {
            CF c1; short8v Nrh, Nrl, Nih, Nil;
            if (t < 3) {
                c1 = loadCF(cw, qr, lane, t + 1);
                Nrh = ldB(0, t + 1); Nrl = ldB(1, t + 1);
                Nih = ldB(2, t + 1); Nil = ldB(3, t + 1);
            }
            short8v Bsh = ldB(4, t), Bsl = ldB(5, t);

            __builtin_amdgcn_s_setprio(1);
            accRr = MF(c0.crh, Brh, accRr);
            accQ  = MF(c0.cdh, Bsh, accQ);
            accRr = MF(c0.crh, Brl, accRr);
            accQ  = MF(c0.cdh, Bsl, accQ);
            accRr = MF(c0.crl, Brh, accRr);
            accQ  = MF(c0.cdl, Bsh, accQ);
            accRr = MF(c0.ncih, Bih, accRr);
            accRr = MF(c0.ncih, Bil, accRr);
            accRr = MF(c0.ncil, Bih, accRr);
            __builtin_amdgcn_s_setprio(0);

            if (t < 3) { c0 = c1; Brh = Nrh; Brl = Nrl; Bih = Nih; Bil = Nil; }
        }
    }

    // ---- epilogue: res_r = accRr; res_i = accRr + accQ + (C0i - C0r) ----
    f32x16 accRi;
    {
        const f32x4* p1 = (const f32x4*)(wsb + KINIT_OFF + (size_t)(((2 + qr) * 2 + qc) * 64 + lane) * 64);
        #pragma unroll
        for (int g = 0; g < 4; ++g) {
            f32x4 d = p1[g];
            #pragma unroll
            for (int j = 0; j < 4; ++j)
                accRi[4 * g + j] = accRr[4 * g + j] + accQ[4 * g + j] + d[j];
        }
    }
    __syncthreads();   // done reading T region; reuse for f32 transpose
    {
        const int c = 32 * qc + lrow;
        #pragma unroll
        for (int g = 0; g < 4; ++g) {
            int rbse = 32 * qr + 8 * g + 4 * lhi;
            f32x4 vr, vi;
            #pragma unroll
            for (int j = 0; j < 4; ++j) { vr[j] = accRr[4 * g + j]; vi[j] = accRi[4 * g + j]; }
            *(f32x4*)(smem + (size_t)(0 * 4352 + c * LSTRIDE + rbse) * 4) = vr;
            *(f32x4*)(smem + (size_t)(1 * 4352 + c * LSTRIDE + rbse) * 4) = vi;
        }
    }
    __syncthreads();
    float* ob = out + b * 8192;
    #pragma unroll
    for (int s = 0; s < 8; ++s) {
        int f = s * 1024 + tid * 4;
        int p = f >> 12, m = (f >> 6) & 63, n = f & 63;
        *(f32x4*)(ob + f) = *(const f32x4*)(smem + (size_t)(p * 4352 + m * LSTRIDE + n) * 4);
    }
}

extern "C" void kernel_launch(void* const* d_in, const int* in_sizes, int n_in,
                              void* d_out, int out_size, void* d_ws, size_t ws_size,
                              hipStream_t stream) {
    const float* x    = (const float*)d_in[0];
    const float* coef = (const float*)d_in[1];
    float* out = (float*)d_out;
    char*  wsb = (char*)d_ws;
    const int B = in_sizes[0] / 8192;   // 2048

    pms_prep_k<<<96, 64, 0, stream>>>(coef, wsb);
    pms_main_k<<<B, 256, KLDS, stream>>>(x, wsb, out);
}